// Round 9
// baseline (215.777 us; speedup 1.0000x reference)
//
#include <hip/hip_runtime.h>
#include <hip/hip_bf16.h>
#include <stdint.h>

// Shapes fixed by the reference: N=8192, F_IN=128, F_OUT=64.
// DTYPE (settled rounds 2-7): inputs and output are f32. Internal bf16 MFMA
// (absmax 3.9e-3 vs threshold 1.49e-2). Harness fixed floor ~78 us.
// Round 9 = round-7 staged K-loop (best, 94.6) + (a) fragment-major whB LDS
// staging (contiguous copy, conflict-free unpadded ds_read_b128), + (b) k3
// fused into k2 via split-K last-block finalization (cnt ticket, threadfence).
// Round-8 lesson: direct-from-L2 B-frag loads regress (latency not hidden);
// LDS staging stays.
typedef float f32x4 __attribute__((ext_vector_type(4)));
typedef short s16x8 __attribute__((ext_vector_type(8)));
typedef unsigned int u32x4 __attribute__((ext_vector_type(4)));

#define L2E 1.44269504088896f  // log2(e)

__device__ __forceinline__ unsigned short f2bf_rne(float f) {
    unsigned int u = __float_as_uint(f);
    u += 0x7fffu + ((u >> 16) & 1u);
    return (unsigned short)(u >> 16);
}

// ---------------------------------------------------------------------------
// k1: Wh = h@W (bf16 MFMA), f1L=(Wh@a1)*log2e, f2L=(Wh@a2)*log2e, and
//     whB = Wh^T in B-fragment-major layout:
//     whB[((jg*4 + b)*64 + lane)*8 + jj] = Wh[j = jg*32 + (lane>>4)*8 + jj]
//                                            [n = b*16 + (lane&15)]
// Also zeroes cnt[blockIdx.x] (split-K ticket for k2's fused finalize).
// Grid: 128 x 256; block = 64 rows (= 2 jg groups).
// ---------------------------------------------------------------------------
__global__ __launch_bounds__(256) void k1_wh(
    const float* __restrict__ hf,
    const float* __restrict__ Wf,
    const float* __restrict__ af,
    unsigned short* __restrict__ whB,
    float* __restrict__ f1L,
    float* __restrict__ f2L,
    int* __restrict__ cnt)
{
    __shared__ __align__(16) unsigned short Wt[64][136];  // [n][k] bf16, pad
    __shared__ __align__(16) unsigned short tb[64][72];   // [n][i_local]
    const int tid  = threadIdx.x;
    const int lane = tid & 63;
    const int w    = tid >> 6;
    const int col  = lane & 15;
    const int quad = lane >> 4;
    const int i0   = blockIdx.x * 64;

    if (tid == 0) cnt[blockIdx.x] = 0;    // ticket reset (ws poisoned 0xAA)

    // stage W (128x64 f32 row-major) -> Wt[n][k] bf16 (transposed)
    #pragma unroll
    for (int it = 0; it < 8; ++it) {
        int fidx = tid + it * 256;        // f32x4 index 0..2047
        int k  = fidx >> 4;               // 0..127
        int n4 = (fidx & 15) << 2;        // 0..60
        f32x4 wv = *(const f32x4*)&Wf[k * 64 + n4];
        #pragma unroll
        for (int e = 0; e < 4; ++e)
            Wt[n4 + e][k] = f2bf_rne(wv[e]);
    }
    __syncthreads();

    f32x4 D[4];
    #pragma unroll
    for (int f = 0; f < 4; ++f) D[f] = (f32x4){0.f, 0.f, 0.f, 0.f};

    const int rowA = i0 + w * 16 + col;  // A operand: m = lane&15
    #pragma unroll
    for (int cs = 0; cs < 4; ++cs) {     // K = 128 in 4 steps of 32
        f32x4 h0 = *(const f32x4*)&hf[(size_t)rowA * 128 + cs * 32 + quad * 8];
        f32x4 h1 = *(const f32x4*)&hf[(size_t)rowA * 128 + cs * 32 + quad * 8 + 4];
        s16x8 A;
        #pragma unroll
        for (int jj = 0; jj < 4; ++jj) {
            A[jj]     = (short)f2bf_rne(h0[jj]);
            A[4 + jj] = (short)f2bf_rne(h1[jj]);
        }
        #pragma unroll
        for (int f = 0; f < 4; ++f) {    // B[k][n]: n = f*16+col, k = cs*32+quad*8+jj
            s16x8 B = *(const s16x8*)&Wt[f * 16 + col][cs * 32 + quad * 8];
            D[f] = __builtin_amdgcn_mfma_f32_16x16x32_bf16(A, B, D[f], 0, 0, 0);
        }
    }

    float a1v[4], a2v[4];
    #pragma unroll
    for (int f = 0; f < 4; ++f) {
        a1v[f] = af[f * 16 + col];
        a2v[f] = af[64 + f * 16 + col];
    }

    // D layout: row = quad*4 + r, col-of-Wh = f*16 + (lane&15)
    #pragma unroll
    for (int r = 0; r < 4; ++r) {
        float s1 = D[0][r]*a1v[0] + D[1][r]*a1v[1] + D[2][r]*a1v[2] + D[3][r]*a1v[3];
        float s2 = D[0][r]*a2v[0] + D[1][r]*a2v[1] + D[2][r]*a2v[2] + D[3][r]*a2v[3];
        #pragma unroll
        for (int d = 1; d < 16; d <<= 1) {  // reduce over the 16 cols
            s1 += __shfl_xor(s1, d, 64);
            s2 += __shfl_xor(s2, d, 64);
        }
        if (col == 0) {
            int i = i0 + w * 16 + quad * 4 + r;
            f1L[i] = s1 * L2E;
            f2L[i] = s2 * L2E;
        }
        #pragma unroll
        for (int f = 0; f < 4; ++f)
            tb[f * 16 + col][w * 16 + quad * 4 + r] = f2bf_rne(D[f][r]);
    }
    __syncthreads();

    // emit whB: 512 chunks of 16 B (2 jg groups x 4 b x 64 lanes)
    for (int idx = tid; idx < 512; idx += 256) {
        int lane_o = idx & 63;
        int bq     = (idx >> 6) & 3;
        int jg_l   = idx >> 8;                       // 0..1
        int col_o  = lane_o & 15, quad_o = lane_o >> 4;
        u32x4 v = *(const u32x4*)&tb[bq * 16 + col_o][jg_l * 32 + quad_o * 8];
        size_t off = (((size_t)((i0 >> 5) + jg_l) * 4 + bq) * 64 + lane_o) * 8;
        *(u32x4*)&whB[off] = v;
    }
}

// ---------------------------------------------------------------------------
// k2: fused attention + split-K finalize. 64 rows x one 1024-j chunk:
//     Apart[s][i][n] = sum_j p_ij*Wh[j][n], rsumP[s][i] = sum_j p_ij.
// whB staged fragment-major into LDS (contiguous 32 KB copies, unpadded
// conflict-free ds_read_b128). After its stores, each block takes a ticket
// on cnt[row_tile]; the 8th arriver sums all 8 slots (own from registers),
// normalizes, applies ELU, writes f32 output. Grid: (128, 8) x 256.
// ---------------------------------------------------------------------------
__global__ __launch_bounds__(256) void k2_attn(
    const unsigned short* __restrict__ whB,
    const float* __restrict__ f1L,
    const float* __restrict__ f2L,
    float* __restrict__ Apart,
    float* __restrict__ rsumP,
    int* __restrict__ cnt,
    float* __restrict__ out)
{
    __shared__ __align__(16) unsigned short BtF[16384];  // 8 jg x 2048, 32 KB
    __shared__ __align__(16) float f2s[256];
    __shared__ int ticket;
    const int tid  = threadIdx.x;
    const int lane = tid & 63;
    const int w    = tid >> 6;
    const int col  = lane & 15;
    const int quad = lane >> 4;
    const int i0   = blockIdx.x * 64;
    const int slot = blockIdx.y;
    const int jb   = slot * 1024;

    const float f1 = f1L[i0 + w * 16 + col];  // A-fragment row m = lane&15

    f32x4 D0 = (f32x4){0.f,0.f,0.f,0.f}, D1 = D0, D2 = D0, D3 = D0, Ds = D0;
    s16x8 ones;
    #pragma unroll
    for (int jj = 0; jj < 8; ++jj) ones[jj] = (short)0x3f80;  // bf16(1.0)

    for (int s = 0; s < 4; ++s) {            // 4 stages x 256 j
        __syncthreads();
        if (tid < 64)
            *(f32x4*)&f2s[tid * 4] = *(const f32x4*)&f2L[jb + (s << 8) + tid * 4];
        {   // contiguous 32 KB fragment-major copy: whB chunk -> BtF
            const unsigned short* src = whB + ((size_t)(jb >> 5) + s * 8) * 2048;
            #pragma unroll
            for (int it = 0; it < 8; ++it) {
                int idx = (tid + it * 256) * 8;      // u32x4 units * 8 ushorts
                *(u32x4*)&BtF[idx] = *(const u32x4*)&src[idx];
            }
        }
        __syncthreads();
        #pragma unroll
        for (int j0 = 0; j0 < 256; j0 += 32) {
            const int jq = j0 + quad * 8;
            f32x4 fa = *(const f32x4*)&f2s[jq];
            f32x4 fb = *(const f32x4*)&f2s[jq + 4];
            unsigned int pb[8];
            #pragma unroll
            for (int e = 0; e < 4; ++e) {
                float u = f1 + fa[e];            // already *log2e
                u = fmaxf(u, 0.01f * u);         // LeakyReLU in log2 domain
                pb[e] = __float_as_uint(__builtin_amdgcn_exp2f(u));
                float v = f1 + fb[e];
                v = fmaxf(v, 0.01f * v);
                pb[4 + e] = __float_as_uint(__builtin_amdgcn_exp2f(v));
            }
            union { u32x4 u4; s16x8 s8; } Au;    // pack truncated bf16 pairs
            Au.u4[0] = __builtin_amdgcn_perm(pb[1], pb[0], 0x07060302u);
            Au.u4[1] = __builtin_amdgcn_perm(pb[3], pb[2], 0x07060302u);
            Au.u4[2] = __builtin_amdgcn_perm(pb[5], pb[4], 0x07060302u);
            Au.u4[3] = __builtin_amdgcn_perm(pb[7], pb[6], 0x07060302u);
            const unsigned short* bf = &BtF[(size_t)(j0 >> 5) * 2048 + lane * 8];
            s16x8 B0 = *(const s16x8*)(bf);
            s16x8 B1 = *(const s16x8*)(bf + 512);
            s16x8 B2 = *(const s16x8*)(bf + 1024);
            s16x8 B3 = *(const s16x8*)(bf + 1536);
            D0 = __builtin_amdgcn_mfma_f32_16x16x32_bf16(Au.s8, B0, D0, 0, 0, 0);
            D1 = __builtin_amdgcn_mfma_f32_16x16x32_bf16(Au.s8, B1, D1, 0, 0, 0);
            D2 = __builtin_amdgcn_mfma_f32_16x16x32_bf16(Au.s8, B2, D2, 0, 0, 0);
            D3 = __builtin_amdgcn_mfma_f32_16x16x32_bf16(Au.s8, B3, D3, 0, 0, 0);
            Ds = __builtin_amdgcn_mfma_f32_16x16x32_bf16(Au.s8, ones, Ds, 0, 0, 0);
        }
    }

    // store own partials (D layout: row = quad*4+r, col n = 16*b + col)
    float* Ap = Apart + (size_t)slot * 524288;
    #pragma unroll
    for (int r = 0; r < 4; ++r) {
        int i = i0 + w * 16 + quad * 4 + r;
        Ap[(size_t)i * 64 +      col] = D0[r];
        Ap[(size_t)i * 64 + 16 + col] = D1[r];
        Ap[(size_t)i * 64 + 32 + col] = D2[r];
        Ap[(size_t)i * 64 + 48 + col] = D3[r];
        if (col == 0) rsumP[slot * 8192 + i] = Ds[r];
    }

    // split-K ticket: 8th arriver for this row-tile finalizes.
    __threadfence();
    __syncthreads();
    if (tid == 0) ticket = atomicAdd(&cnt[blockIdx.x], 1);
    __syncthreads();
    if (ticket != 7) return;
    __threadfence();  // acquire side: other slots' stores now visible

    #pragma unroll
    for (int r = 0; r < 4; ++r) {
        int i = i0 + w * 16 + quad * 4 + r;
        float den = Ds[r];
        float num0 = D0[r], num1 = D1[r], num2 = D2[r], num3 = D3[r];
        #pragma unroll
        for (int s = 0; s < 8; ++s) {
            if (s == slot) continue;
            den  += rsumP[s * 8192 + i];
            const float* As = Apart + (size_t)s * 524288 + (size_t)i * 64;
            num0 += As[     col];
            num1 += As[16 + col];
            num2 += As[32 + col];
            num3 += As[48 + col];
        }
        float rden = 1.f / den;
        float v0 = num0 * rden, v1 = num1 * rden;
        float v2 = num2 * rden, v3 = num3 * rden;
        v0 = v0 > 0.f ? v0 : (__builtin_amdgcn_exp2f(v0 * L2E) - 1.f);
        v1 = v1 > 0.f ? v1 : (__builtin_amdgcn_exp2f(v1 * L2E) - 1.f);
        v2 = v2 > 0.f ? v2 : (__builtin_amdgcn_exp2f(v2 * L2E) - 1.f);
        v3 = v3 > 0.f ? v3 : (__builtin_amdgcn_exp2f(v3 * L2E) - 1.f);
        out[(size_t)i * 64 +      col] = v0;
        out[(size_t)i * 64 + 16 + col] = v1;
        out[(size_t)i * 64 + 32 + col] = v2;
        out[(size_t)i * 64 + 48 + col] = v3;
    }
}

// ---------------------------------------------------------------------------
extern "C" void kernel_launch(void* const* d_in, const int* in_sizes, int n_in,
                              void* d_out, int out_size, void* d_ws, size_t ws_size,
                              hipStream_t stream) {
    const float* h = (const float*)d_in[0];  // 8192x128 f32
    const float* W = (const float*)d_in[1];  // 128x64 f32
    const float* a = (const float*)d_in[2];  // 128x1 f32
    float* out = (float*)d_out;              // 8192x64 f32

    char* ws = (char*)d_ws;
    unsigned short* whB = (unsigned short*)ws;        // 1 MB fragment-major Wh^T
    float* f1L   = (float*)(ws + 1048576);            // 32 KB
    float* f2L   = (float*)(ws + 1081344);            // 32 KB
    int*   cnt   = (int*)  (ws + 1114112);            // 512 B (128 tickets)
    float* Apart = (float*)(ws + 1114624);            // 8 x 8192x64 f32 = 16 MB
    float* rsumP = (float*)(ws + 17891840);           // 8 x 8192 f32 = 256 KB
    // total ws ~18.1 MB (ws_size ~256 MB per fill counters)

    k1_wh<<<128, 256, 0, stream>>>(h, W, a, whB, f1L, f2L, cnt);
    k2_attn<<<dim3(128, 8), 256, 0, stream>>>(whB, f1L, f2L, Apart, rsumP, cnt, out);
}

// Round 10
// 92.200 us; speedup vs baseline: 2.3403x; 2.3403x over previous
//
#include <hip/hip_runtime.h>
#include <hip/hip_bf16.h>
#include <stdint.h>

// Shapes fixed by the reference: N=8192, F_IN=128, F_OUT=64.
// DTYPE (settled): f32 in/out, bf16 MFMA internal (absmax 3.9e-3 vs 1.49e-2).
// Harness fixed floor ~79 us (256 MB ws re-poison is timed).
// Round 10 = round-7 three-kernel structure (best, 94.6 us) + round-9's
// verified fragment-major whB LDS staging (SQ_LDS_BANK_CONFLICT=0).
// Round-9 lesson (hard): per-block __threadfence() split-K finalize = L2
// writeback storm on CDNA4 (per-XCD L2, device-scope release flushes it);
// k2 155 us. Cross-block combine stays in its own dispatch (k3).
typedef float f32x4 __attribute__((ext_vector_type(4)));
typedef short s16x8 __attribute__((ext_vector_type(8)));
typedef unsigned int u32x4 __attribute__((ext_vector_type(4)));

#define L2E 1.44269504088896f  // log2(e)

__device__ __forceinline__ unsigned short f2bf_rne(float f) {
    unsigned int u = __float_as_uint(f);
    u += 0x7fffu + ((u >> 16) & 1u);
    return (unsigned short)(u >> 16);
}

// ---------------------------------------------------------------------------
// k1: Wh = h@W (bf16 MFMA), f1L=(Wh@a1)*log2e, f2L=(Wh@a2)*log2e, and
//     whB = Wh^T in B-fragment-major layout:
//     whB[((jg*4 + b)*64 + lane)*8 + jj] = Wh[j = jg*32 + (lane>>4)*8 + jj]
//                                            [n = b*16 + (lane&15)]
// Grid: 128 x 256; block = 64 rows (= 2 jg groups).
// ---------------------------------------------------------------------------
__global__ __launch_bounds__(256) void k1_wh(
    const float* __restrict__ hf,
    const float* __restrict__ Wf,
    const float* __restrict__ af,
    unsigned short* __restrict__ whB,
    float* __restrict__ f1L,
    float* __restrict__ f2L)
{
    __shared__ __align__(16) unsigned short Wt[64][136];  // [n][k] bf16, pad
    __shared__ __align__(16) unsigned short tb[64][72];   // [n][i_local]
    const int tid  = threadIdx.x;
    const int lane = tid & 63;
    const int w    = tid >> 6;
    const int col  = lane & 15;
    const int quad = lane >> 4;
    const int i0   = blockIdx.x * 64;

    // stage W (128x64 f32 row-major) -> Wt[n][k] bf16 (transposed)
    #pragma unroll
    for (int it = 0; it < 8; ++it) {
        int fidx = tid + it * 256;        // f32x4 index 0..2047
        int k  = fidx >> 4;               // 0..127
        int n4 = (fidx & 15) << 2;        // 0..60
        f32x4 wv = *(const f32x4*)&Wf[k * 64 + n4];
        #pragma unroll
        for (int e = 0; e < 4; ++e)
            Wt[n4 + e][k] = f2bf_rne(wv[e]);
    }
    __syncthreads();

    f32x4 D[4];
    #pragma unroll
    for (int f = 0; f < 4; ++f) D[f] = (f32x4){0.f, 0.f, 0.f, 0.f};

    const int rowA = i0 + w * 16 + col;  // A operand: m = lane&15
    #pragma unroll
    for (int cs = 0; cs < 4; ++cs) {     // K = 128 in 4 steps of 32
        f32x4 h0 = *(const f32x4*)&hf[(size_t)rowA * 128 + cs * 32 + quad * 8];
        f32x4 h1 = *(const f32x4*)&hf[(size_t)rowA * 128 + cs * 32 + quad * 8 + 4];
        s16x8 A;
        #pragma unroll
        for (int jj = 0; jj < 4; ++jj) {
            A[jj]     = (short)f2bf_rne(h0[jj]);
            A[4 + jj] = (short)f2bf_rne(h1[jj]);
        }
        #pragma unroll
        for (int f = 0; f < 4; ++f) {    // B[k][n]: n = f*16+col, k = cs*32+quad*8+jj
            s16x8 B = *(const s16x8*)&Wt[f * 16 + col][cs * 32 + quad * 8];
            D[f] = __builtin_amdgcn_mfma_f32_16x16x32_bf16(A, B, D[f], 0, 0, 0);
        }
    }

    float a1v[4], a2v[4];
    #pragma unroll
    for (int f = 0; f < 4; ++f) {
        a1v[f] = af[f * 16 + col];
        a2v[f] = af[64 + f * 16 + col];
    }

    // D layout: row = quad*4 + r, col-of-Wh = f*16 + (lane&15)
    #pragma unroll
    for (int r = 0; r < 4; ++r) {
        float s1 = D[0][r]*a1v[0] + D[1][r]*a1v[1] + D[2][r]*a1v[2] + D[3][r]*a1v[3];
        float s2 = D[0][r]*a2v[0] + D[1][r]*a2v[1] + D[2][r]*a2v[2] + D[3][r]*a2v[3];
        #pragma unroll
        for (int d = 1; d < 16; d <<= 1) {  // reduce over the 16 cols
            s1 += __shfl_xor(s1, d, 64);
            s2 += __shfl_xor(s2, d, 64);
        }
        if (col == 0) {
            int i = i0 + w * 16 + quad * 4 + r;
            f1L[i] = s1 * L2E;
            f2L[i] = s2 * L2E;
        }
        #pragma unroll
        for (int f = 0; f < 4; ++f)
            tb[f * 16 + col][w * 16 + quad * 4 + r] = f2bf_rne(D[f][r]);
    }
    __syncthreads();

    // emit whB: 512 chunks of 16 B (2 jg groups x 4 b x 64 lanes)
    for (int idx = tid; idx < 512; idx += 256) {
        int lane_o = idx & 63;
        int bq     = (idx >> 6) & 3;
        int jg_l   = idx >> 8;                       // 0..1
        int col_o  = lane_o & 15, quad_o = lane_o >> 4;
        u32x4 v = *(const u32x4*)&tb[bq * 16 + col_o][jg_l * 32 + quad_o * 8];
        size_t off = (((size_t)((i0 >> 5) + jg_l) * 4 + bq) * 64 + lane_o) * 8;
        *(u32x4*)&whB[off] = v;
    }
}

// ---------------------------------------------------------------------------
// k2: fused attention partials: 64 rows x one 1024-j chunk:
//     Apart[s][i][n] = sum_j p_ij*Wh[j][n], rsumP[s][i] = sum_j p_ij.
// whB staged fragment-major into LDS (contiguous 32 KB copies; unpadded
// ds_read_b128, SQ_LDS_BANK_CONFLICT=0 verified round 9). Plain stores,
// no atomics, NO fences. Grid: (128 row-tiles, 8 j-chunks) x 256 thr.
// ---------------------------------------------------------------------------
__global__ __launch_bounds__(256) void k2_attn(
    const unsigned short* __restrict__ whB,
    const float* __restrict__ f1L,
    const float* __restrict__ f2L,
    float* __restrict__ Apart,
    float* __restrict__ rsumP)
{
    __shared__ __align__(16) unsigned short BtF[16384];  // 8 jg x 2048, 32 KB
    __shared__ __align__(16) float f2s[256];
    const int tid  = threadIdx.x;
    const int lane = tid & 63;
    const int w    = tid >> 6;
    const int col  = lane & 15;
    const int quad = lane >> 4;
    const int i0   = blockIdx.x * 64;
    const int jb   = blockIdx.y * 1024;

    const float f1 = f1L[i0 + w * 16 + col];  // A-fragment row m = lane&15

    f32x4 D0 = (f32x4){0.f,0.f,0.f,0.f}, D1 = D0, D2 = D0, D3 = D0, Ds = D0;
    s16x8 ones;
    #pragma unroll
    for (int jj = 0; jj < 8; ++jj) ones[jj] = (short)0x3f80;  // bf16(1.0)

    for (int s = 0; s < 4; ++s) {            // 4 stages x 256 j
        __syncthreads();
        if (tid < 64)
            *(f32x4*)&f2s[tid * 4] = *(const f32x4*)&f2L[jb + (s << 8) + tid * 4];
        {   // contiguous 32 KB fragment-major copy: whB chunk -> BtF
            const unsigned short* src = whB + ((size_t)(jb >> 5) + s * 8) * 2048;
            #pragma unroll
            for (int it = 0; it < 8; ++it) {
                int idx = (tid + it * 256) * 8;      // u32x4 units * 8 ushorts
                *(u32x4*)&BtF[idx] = *(const u32x4*)&src[idx];
            }
        }
        __syncthreads();
        #pragma unroll
        for (int j0 = 0; j0 < 256; j0 += 32) {
            const int jq = j0 + quad * 8;
            f32x4 fa = *(const f32x4*)&f2s[jq];
            f32x4 fb = *(const f32x4*)&f2s[jq + 4];
            unsigned int pb[8];
            #pragma unroll
            for (int e = 0; e < 4; ++e) {
                float u = f1 + fa[e];            // already *log2e
                u = fmaxf(u, 0.01f * u);         // LeakyReLU in log2 domain
                pb[e] = __float_as_uint(__builtin_amdgcn_exp2f(u));
                float v = f1 + fb[e];
                v = fmaxf(v, 0.01f * v);
                pb[4 + e] = __float_as_uint(__builtin_amdgcn_exp2f(v));
            }
            union { u32x4 u4; s16x8 s8; } Au;    // pack truncated bf16 pairs
            Au.u4[0] = __builtin_amdgcn_perm(pb[1], pb[0], 0x07060302u);
            Au.u4[1] = __builtin_amdgcn_perm(pb[3], pb[2], 0x07060302u);
            Au.u4[2] = __builtin_amdgcn_perm(pb[5], pb[4], 0x07060302u);
            Au.u4[3] = __builtin_amdgcn_perm(pb[7], pb[6], 0x07060302u);
            const unsigned short* bf = &BtF[(size_t)(j0 >> 5) * 2048 + lane * 8];
            s16x8 B0 = *(const s16x8*)(bf);
            s16x8 B1 = *(const s16x8*)(bf + 512);
            s16x8 B2 = *(const s16x8*)(bf + 1024);
            s16x8 B3 = *(const s16x8*)(bf + 1536);
            D0 = __builtin_amdgcn_mfma_f32_16x16x32_bf16(Au.s8, B0, D0, 0, 0, 0);
            D1 = __builtin_amdgcn_mfma_f32_16x16x32_bf16(Au.s8, B1, D1, 0, 0, 0);
            D2 = __builtin_amdgcn_mfma_f32_16x16x32_bf16(Au.s8, B2, D2, 0, 0, 0);
            D3 = __builtin_amdgcn_mfma_f32_16x16x32_bf16(Au.s8, B3, D3, 0, 0, 0);
            Ds = __builtin_amdgcn_mfma_f32_16x16x32_bf16(Au.s8, ones, Ds, 0, 0, 0);
        }
    }

    float* Ap = Apart + (size_t)blockIdx.y * 524288;
    #pragma unroll
    for (int r = 0; r < 4; ++r) {   // D layout: row = quad*4+r, col n = 16*b + col
        int i = i0 + w * 16 + quad * 4 + r;
        Ap[(size_t)i * 64 +      col] = D0[r];
        Ap[(size_t)i * 64 + 16 + col] = D1[r];
        Ap[(size_t)i * 64 + 32 + col] = D2[r];
        Ap[(size_t)i * 64 + 48 + col] = D3[r];
        if (col == 0) rsumP[blockIdx.y * 8192 + i] = Ds[r];
    }
}

// ---------------------------------------------------------------------------
// k3: out(f32) = elu( sum_s Apart[s] / sum_s rsumP[s] ), vectorized x4.
// Kernel-boundary = the cross-block fence (round-9 lesson). Grid: 512 x 256.
// ---------------------------------------------------------------------------
__global__ __launch_bounds__(256) void k3_combine(
    const float* __restrict__ Apart,
    const float* __restrict__ rsumP,
    float* __restrict__ out)
{
    int gid = blockIdx.x * 256 + threadIdx.x;  // 0 .. 131071
    int i  = gid >> 4;
    int c4 = (gid & 15) << 2;
    f32x4 num = (f32x4){0.f, 0.f, 0.f, 0.f};
    float den = 0.f;
    #pragma unroll
    for (int s = 0; s < 8; ++s) {
        num += *(const f32x4*)&Apart[(size_t)s * 524288 + (size_t)i * 64 + c4];
        den += rsumP[s * 8192 + i];
    }
    float rden = 1.f / den;
    f32x4 o;
    #pragma unroll
    for (int e = 0; e < 4; ++e) {
        float v = num[e] * rden;
        o[e] = v > 0.f ? v : (__builtin_amdgcn_exp2f(v * L2E) - 1.f);
    }
    *(f32x4*)&out[(size_t)i * 64 + c4] = o;
}

// ---------------------------------------------------------------------------
extern "C" void kernel_launch(void* const* d_in, const int* in_sizes, int n_in,
                              void* d_out, int out_size, void* d_ws, size_t ws_size,
                              hipStream_t stream) {
    const float* h = (const float*)d_in[0];  // 8192x128 f32
    const float* W = (const float*)d_in[1];  // 128x64 f32
    const float* a = (const float*)d_in[2];  // 128x1 f32
    float* out = (float*)d_out;              // 8192x64 f32

    char* ws = (char*)d_ws;
    unsigned short* whB = (unsigned short*)ws;        // 1 MB fragment-major Wh^T
    float* f1L   = (float*)(ws + 1048576);            // 32 KB
    float* f2L   = (float*)(ws + 1081344);            // 32 KB
    float* Apart = (float*)(ws + 1114112);            // 8 x 8192x64 f32 = 16 MB
    float* rsumP = (float*)(ws + 17891328);           // 8 x 8192 f32 = 256 KB
    // total ws ~18.1 MB (ws_size ~256 MB per fill counters)

    k1_wh<<<128, 256, 0, stream>>>(h, W, a, whB, f1L, f2L);
    k2_attn<<<dim3(128, 8), 256, 0, stream>>>(whB, f1L, f2L, Apart, rsumP);
    k3_combine<<<512, 256, 0, stream>>>(Apart, rsumP, out);
}

// Round 11
// 85.553 us; speedup vs baseline: 2.5221x; 1.0777x over previous
//
#include <hip/hip_runtime.h>
#include <hip/hip_bf16.h>
#include <stdint.h>

// Shapes fixed by the reference: N=8192, F_IN=128, F_OUT=64.
// DTYPE (settled): f32 in/out, bf16 MFMA internal.
// Harness fixed floor ~79 us (256 MB ws re-poison is timed).
// Round 11 = round-10 (92.2 us best) + (a) 128-row/512-thr k2 blocks (8 waves
// share each staged tile -> whB L2 staging traffic 128->64 MB), (b) bf16
// numerator partials (Apart 16->8 MB; rsumP stays f32 so denom exact).
// Hard lessons: no per-block __threadfence (R9 L2 storm); LDS staging beats
// direct-L2 B-frag loads (R8); cross-block combine stays its own dispatch.
typedef float f32x4 __attribute__((ext_vector_type(4)));
typedef short s16x8 __attribute__((ext_vector_type(8)));
typedef short s16x4 __attribute__((ext_vector_type(4)));
typedef unsigned int u32x4 __attribute__((ext_vector_type(4)));

#define L2E 1.44269504088896f  // log2(e)

__device__ __forceinline__ float bf2f(unsigned short u) {
    return __uint_as_float(((unsigned int)u) << 16);
}
__device__ __forceinline__ unsigned short f2bf_rne(float f) {
    unsigned int u = __float_as_uint(f);
    u += 0x7fffu + ((u >> 16) & 1u);
    return (unsigned short)(u >> 16);
}

// ---------------------------------------------------------------------------
// k1: Wh = h@W (bf16 MFMA), f1L=(Wh@a1)*log2e, f2L=(Wh@a2)*log2e, and
//     whB = Wh^T in B-fragment-major layout:
//     whB[((jg*4 + b)*64 + lane)*8 + jj] = Wh[j = jg*32 + (lane>>4)*8 + jj]
//                                            [n = b*16 + (lane&15)]
// Grid: 128 x 256; block = 64 rows. [unchanged from round 10 — proven]
// ---------------------------------------------------------------------------
__global__ __launch_bounds__(256) void k1_wh(
    const float* __restrict__ hf,
    const float* __restrict__ Wf,
    const float* __restrict__ af,
    unsigned short* __restrict__ whB,
    float* __restrict__ f1L,
    float* __restrict__ f2L)
{
    __shared__ __align__(16) unsigned short Wt[64][136];  // [n][k] bf16, pad
    __shared__ __align__(16) unsigned short tb[64][72];   // [n][i_local]
    const int tid  = threadIdx.x;
    const int lane = tid & 63;
    const int w    = tid >> 6;
    const int col  = lane & 15;
    const int quad = lane >> 4;
    const int i0   = blockIdx.x * 64;

    // stage W (128x64 f32 row-major) -> Wt[n][k] bf16 (transposed)
    #pragma unroll
    for (int it = 0; it < 8; ++it) {
        int fidx = tid + it * 256;        // f32x4 index 0..2047
        int k  = fidx >> 4;               // 0..127
        int n4 = (fidx & 15) << 2;        // 0..60
        f32x4 wv = *(const f32x4*)&Wf[k * 64 + n4];
        #pragma unroll
        for (int e = 0; e < 4; ++e)
            Wt[n4 + e][k] = f2bf_rne(wv[e]);
    }
    __syncthreads();

    f32x4 D[4];
    #pragma unroll
    for (int f = 0; f < 4; ++f) D[f] = (f32x4){0.f, 0.f, 0.f, 0.f};

    const int rowA = i0 + w * 16 + col;  // A operand: m = lane&15
    #pragma unroll
    for (int cs = 0; cs < 4; ++cs) {     // K = 128 in 4 steps of 32
        f32x4 h0 = *(const f32x4*)&hf[(size_t)rowA * 128 + cs * 32 + quad * 8];
        f32x4 h1 = *(const f32x4*)&hf[(size_t)rowA * 128 + cs * 32 + quad * 8 + 4];
        s16x8 A;
        #pragma unroll
        for (int jj = 0; jj < 4; ++jj) {
            A[jj]     = (short)f2bf_rne(h0[jj]);
            A[4 + jj] = (short)f2bf_rne(h1[jj]);
        }
        #pragma unroll
        for (int f = 0; f < 4; ++f) {    // B[k][n]: n = f*16+col, k = cs*32+quad*8+jj
            s16x8 B = *(const s16x8*)&Wt[f * 16 + col][cs * 32 + quad * 8];
            D[f] = __builtin_amdgcn_mfma_f32_16x16x32_bf16(A, B, D[f], 0, 0, 0);
        }
    }

    float a1v[4], a2v[4];
    #pragma unroll
    for (int f = 0; f < 4; ++f) {
        a1v[f] = af[f * 16 + col];
        a2v[f] = af[64 + f * 16 + col];
    }

    // D layout: row = quad*4 + r, col-of-Wh = f*16 + (lane&15)
    #pragma unroll
    for (int r = 0; r < 4; ++r) {
        float s1 = D[0][r]*a1v[0] + D[1][r]*a1v[1] + D[2][r]*a1v[2] + D[3][r]*a1v[3];
        float s2 = D[0][r]*a2v[0] + D[1][r]*a2v[1] + D[2][r]*a2v[2] + D[3][r]*a2v[3];
        #pragma unroll
        for (int d = 1; d < 16; d <<= 1) {  // reduce over the 16 cols
            s1 += __shfl_xor(s1, d, 64);
            s2 += __shfl_xor(s2, d, 64);
        }
        if (col == 0) {
            int i = i0 + w * 16 + quad * 4 + r;
            f1L[i] = s1 * L2E;
            f2L[i] = s2 * L2E;
        }
        #pragma unroll
        for (int f = 0; f < 4; ++f)
            tb[f * 16 + col][w * 16 + quad * 4 + r] = f2bf_rne(D[f][r]);
    }
    __syncthreads();

    // emit whB: 512 chunks of 16 B (2 jg groups x 4 b x 64 lanes)
    for (int idx = tid; idx < 512; idx += 256) {
        int lane_o = idx & 63;
        int bq     = (idx >> 6) & 3;
        int jg_l   = idx >> 8;                       // 0..1
        int col_o  = lane_o & 15, quad_o = lane_o >> 4;
        u32x4 v = *(const u32x4*)&tb[bq * 16 + col_o][jg_l * 32 + quad_o * 8];
        size_t off = (((size_t)((i0 >> 5) + jg_l) * 4 + bq) * 64 + lane_o) * 8;
        *(u32x4*)&whB[off] = v;
    }
}

// ---------------------------------------------------------------------------
// k2: fused attention partials: 128 rows x one 1024-j chunk per block,
// 8 row-group waves share each staged tile (halves whB L2 traffic vs 64-row
// blocks). Apart partials stored bf16 (rsumP stays f32: exact denominator).
//     Apart[s][i][n] = bf16(sum_j p_ij*Wh[j][n]), rsumP[s][i] = sum_j p_ij.
// Grid: (64 row-tiles, 8 j-chunks) x 512 thr. 2 blocks/CU (16 waves).
// ---------------------------------------------------------------------------
__global__ __launch_bounds__(512, 4) void k2_attn(
    const unsigned short* __restrict__ whB,
    const float* __restrict__ f1L,
    const float* __restrict__ f2L,
    unsigned short* __restrict__ Apart,
    float* __restrict__ rsumP)
{
    __shared__ __align__(16) unsigned short BtF[16384];  // 8 jg x 2048, 32 KB
    __shared__ __align__(16) float f2s[256];
    const int tid  = threadIdx.x;
    const int lane = tid & 63;
    const int w    = tid >> 6;       // row-group 0..7
    const int col  = lane & 15;
    const int quad = lane >> 4;
    const int i0   = blockIdx.x * 128;
    const int jb   = blockIdx.y * 1024;

    const float f1 = f1L[i0 + w * 16 + col];  // A-fragment row m = lane&15

    f32x4 D0 = (f32x4){0.f,0.f,0.f,0.f}, D1 = D0, D2 = D0, D3 = D0, Ds = D0;
    s16x8 ones;
    #pragma unroll
    for (int jj = 0; jj < 8; ++jj) ones[jj] = (short)0x3f80;  // bf16(1.0)

    for (int s = 0; s < 4; ++s) {            // 4 stages x 256 j
        __syncthreads();
        if (tid < 64)
            *(f32x4*)&f2s[tid * 4] = *(const f32x4*)&f2L[jb + (s << 8) + tid * 4];
        {   // contiguous 32 KB fragment-major copy: whB chunk -> BtF
            const unsigned short* src = whB + ((size_t)(jb >> 5) + s * 8) * 2048;
            #pragma unroll
            for (int it = 0; it < 4; ++it) {
                int idx = (tid + it * 512) * 8;      // u32x4 units * 8 ushorts
                *(u32x4*)&BtF[idx] = *(const u32x4*)&src[idx];
            }
        }
        __syncthreads();
        #pragma unroll
        for (int j0 = 0; j0 < 256; j0 += 32) {
            const int jq = j0 + quad * 8;
            f32x4 fa = *(const f32x4*)&f2s[jq];
            f32x4 fb = *(const f32x4*)&f2s[jq + 4];
            unsigned int pb[8];
            #pragma unroll
            for (int e = 0; e < 4; ++e) {
                float u = f1 + fa[e];            // already *log2e
                u = fmaxf(u, 0.01f * u);         // LeakyReLU in log2 domain
                pb[e] = __float_as_uint(__builtin_amdgcn_exp2f(u));
                float v = f1 + fb[e];
                v = fmaxf(v, 0.01f * v);
                pb[4 + e] = __float_as_uint(__builtin_amdgcn_exp2f(v));
            }
            union { u32x4 u4; s16x8 s8; } Au;    // pack truncated bf16 pairs
            Au.u4[0] = __builtin_amdgcn_perm(pb[1], pb[0], 0x07060302u);
            Au.u4[1] = __builtin_amdgcn_perm(pb[3], pb[2], 0x07060302u);
            Au.u4[2] = __builtin_amdgcn_perm(pb[5], pb[4], 0x07060302u);
            Au.u4[3] = __builtin_amdgcn_perm(pb[7], pb[6], 0x07060302u);
            const unsigned short* bf = &BtF[(size_t)(j0 >> 5) * 2048 + lane * 8];
            s16x8 B0 = *(const s16x8*)(bf);
            s16x8 B1 = *(const s16x8*)(bf + 512);
            s16x8 B2 = *(const s16x8*)(bf + 1024);
            s16x8 B3 = *(const s16x8*)(bf + 1536);
            D0 = __builtin_amdgcn_mfma_f32_16x16x32_bf16(Au.s8, B0, D0, 0, 0, 0);
            D1 = __builtin_amdgcn_mfma_f32_16x16x32_bf16(Au.s8, B1, D1, 0, 0, 0);
            D2 = __builtin_amdgcn_mfma_f32_16x16x32_bf16(Au.s8, B2, D2, 0, 0, 0);
            D3 = __builtin_amdgcn_mfma_f32_16x16x32_bf16(Au.s8, B3, D3, 0, 0, 0);
            Ds = __builtin_amdgcn_mfma_f32_16x16x32_bf16(Au.s8, ones, Ds, 0, 0, 0);
        }
    }

    unsigned short* Ap = Apart + (size_t)blockIdx.y * 524288;
    #pragma unroll
    for (int r = 0; r < 4; ++r) {   // D layout: row = quad*4+r, col n = 16*b + col
        int i = i0 + w * 16 + quad * 4 + r;
        Ap[(size_t)i * 64 +      col] = f2bf_rne(D0[r]);
        Ap[(size_t)i * 64 + 16 + col] = f2bf_rne(D1[r]);
        Ap[(size_t)i * 64 + 32 + col] = f2bf_rne(D2[r]);
        Ap[(size_t)i * 64 + 48 + col] = f2bf_rne(D3[r]);
        if (col == 0) rsumP[blockIdx.y * 8192 + i] = Ds[r];
    }
}

// ---------------------------------------------------------------------------
// k3: out(f32) = elu( sum_s bf2f(Apart[s]) / sum_s rsumP[s] ), x4 per thread.
// Kernel boundary = the cross-block fence (round-9 lesson). Grid: 512 x 256.
// ---------------------------------------------------------------------------
__global__ __launch_bounds__(256) void k3_combine(
    const unsigned short* __restrict__ Apart,
    const float* __restrict__ rsumP,
    float* __restrict__ out)
{
    int gid = blockIdx.x * 256 + threadIdx.x;  // 0 .. 131071
    int i  = gid >> 4;
    int c4 = (gid & 15) << 2;
    f32x4 num = (f32x4){0.f, 0.f, 0.f, 0.f};
    float den = 0.f;
    #pragma unroll
    for (int s = 0; s < 8; ++s) {
        s16x4 pv = *(const s16x4*)&Apart[(size_t)s * 524288 + (size_t)i * 64 + c4];
        #pragma unroll
        for (int e = 0; e < 4; ++e) num[e] += bf2f((unsigned short)pv[e]);
        den += rsumP[s * 8192 + i];
    }
    float rden = 1.f / den;
    f32x4 o;
    #pragma unroll
    for (int e = 0; e < 4; ++e) {
        float v = num[e] * rden;
        o[e] = v > 0.f ? v : (__builtin_amdgcn_exp2f(v * L2E) - 1.f);
    }
    *(f32x4*)&out[(size_t)i * 64 + c4] = o;
}

// ---------------------------------------------------------------------------
extern "C" void kernel_launch(void* const* d_in, const int* in_sizes, int n_in,
                              void* d_out, int out_size, void* d_ws, size_t ws_size,
                              hipStream_t stream) {
    const float* h = (const float*)d_in[0];  // 8192x128 f32
    const float* W = (const float*)d_in[1];  // 128x64 f32
    const float* a = (const float*)d_in[2];  // 128x1 f32
    float* out = (float*)d_out;              // 8192x64 f32

    char* ws = (char*)d_ws;
    unsigned short* whB   = (unsigned short*)ws;      // 1 MB fragment-major Wh^T
    float* f1L            = (float*)(ws + 1048576);   // 32 KB
    float* f2L            = (float*)(ws + 1081344);   // 32 KB
    unsigned short* Apart = (unsigned short*)(ws + 1114112);  // 8 x 8192x64 bf16 = 8 MB
    float* rsumP          = (float*)(ws + 9502720);   // 8 x 8192 f32 = 256 KB
    // total ws ~9.8 MB (ws_size ~256 MB per fill counters)

    k1_wh<<<128, 256, 0, stream>>>(h, W, a, whB, f1L, f2L);
    k2_attn<<<dim3(64, 8), 512, 0, stream>>>(whB, f1L, f2L, Apart, rsumP);
    k3_combine<<<512, 256, 0, stream>>>(Apart, rsumP, out);
}

// Round 12
// 84.499 us; speedup vs baseline: 2.5536x; 1.0125x over previous
//
#include <hip/hip_runtime.h>
#include <hip/hip_bf16.h>
#include <stdint.h>

// Shapes fixed by the reference: N=8192, F_IN=128, F_OUT=64.
// DTYPE (settled): f32 in/out, bf16 MFMA internal.
// Harness fixed floor ~78.8 us (256 MB ws re-poison is timed; untouchable).
// Round 12 = round-11 (85.55 us best) + exp elimination in k2:
//   exp(LeakyReLU(f1+f2)) = max(e^{f1}e^{f2}, e^{.01 f1}e^{.01 f2})
// k1 precomputes g1,g2 (rows) and E1,E2 (cols) — 16K exps replace 134M.
// k2 inner: p = max(g1*E1_j, g2*E2_j) — zero transcendentals (v_exp_f32 is
// quarter-rate; it was ~half of k2's VALU critical path).
// Hard lessons: no per-block __threadfence (R9 L2 storm); LDS staging beats
// direct-L2 B-frag loads (R8); cross-block combine stays its own dispatch.
typedef float f32x4 __attribute__((ext_vector_type(4)));
typedef short s16x8 __attribute__((ext_vector_type(8)));
typedef short s16x4 __attribute__((ext_vector_type(4)));
typedef unsigned int u32x4 __attribute__((ext_vector_type(4)));

#define L2E 1.44269504088896f  // log2(e)

__device__ __forceinline__ float bf2f(unsigned short u) {
    return __uint_as_float(((unsigned int)u) << 16);
}
__device__ __forceinline__ unsigned short f2bf_rne(float f) {
    unsigned int u = __float_as_uint(f);
    u += 0x7fffu + ((u >> 16) & 1u);
    return (unsigned short)(u >> 16);
}

// ---------------------------------------------------------------------------
// k1: Wh = h@W (bf16 MFMA); per row i: g1=e^{f1}, g2=e^{.01 f1};
//     per col j (same index space): E1=e^{f2}, E2=e^{.01 f2};
//     whB = Wh^T in B-fragment-major layout:
//     whB[((jg*4 + b)*64 + lane)*8 + jj] = Wh[j = jg*32 + (lane>>4)*8 + jj]
//                                            [n = b*16 + (lane&15)]
// Grid: 128 x 256; block = 64 rows.
// ---------------------------------------------------------------------------
__global__ __launch_bounds__(256) void k1_wh(
    const float* __restrict__ hf,
    const float* __restrict__ Wf,
    const float* __restrict__ af,
    unsigned short* __restrict__ whB,
    float* __restrict__ g1L,
    float* __restrict__ g2L,
    float* __restrict__ E1L,
    float* __restrict__ E2L)
{
    __shared__ __align__(16) unsigned short Wt[64][136];  // [n][k] bf16, pad
    __shared__ __align__(16) unsigned short tb[64][72];   // [n][i_local]
    const int tid  = threadIdx.x;
    const int lane = tid & 63;
    const int w    = tid >> 6;
    const int col  = lane & 15;
    const int quad = lane >> 4;
    const int i0   = blockIdx.x * 64;

    // stage W (128x64 f32 row-major) -> Wt[n][k] bf16 (transposed)
    #pragma unroll
    for (int it = 0; it < 8; ++it) {
        int fidx = tid + it * 256;        // f32x4 index 0..2047
        int k  = fidx >> 4;               // 0..127
        int n4 = (fidx & 15) << 2;        // 0..60
        f32x4 wv = *(const f32x4*)&Wf[k * 64 + n4];
        #pragma unroll
        for (int e = 0; e < 4; ++e)
            Wt[n4 + e][k] = f2bf_rne(wv[e]);
    }
    __syncthreads();

    f32x4 D[4];
    #pragma unroll
    for (int f = 0; f < 4; ++f) D[f] = (f32x4){0.f, 0.f, 0.f, 0.f};

    const int rowA = i0 + w * 16 + col;  // A operand: m = lane&15
    #pragma unroll
    for (int cs = 0; cs < 4; ++cs) {     // K = 128 in 4 steps of 32
        f32x4 h0 = *(const f32x4*)&hf[(size_t)rowA * 128 + cs * 32 + quad * 8];
        f32x4 h1 = *(const f32x4*)&hf[(size_t)rowA * 128 + cs * 32 + quad * 8 + 4];
        s16x8 A;
        #pragma unroll
        for (int jj = 0; jj < 4; ++jj) {
            A[jj]     = (short)f2bf_rne(h0[jj]);
            A[4 + jj] = (short)f2bf_rne(h1[jj]);
        }
        #pragma unroll
        for (int f = 0; f < 4; ++f) {    // B[k][n]: n = f*16+col, k = cs*32+quad*8+jj
            s16x8 B = *(const s16x8*)&Wt[f * 16 + col][cs * 32 + quad * 8];
            D[f] = __builtin_amdgcn_mfma_f32_16x16x32_bf16(A, B, D[f], 0, 0, 0);
        }
    }

    float a1v[4], a2v[4];
    #pragma unroll
    for (int f = 0; f < 4; ++f) {
        a1v[f] = af[f * 16 + col];
        a2v[f] = af[64 + f * 16 + col];
    }

    // D layout: row = quad*4 + r, col-of-Wh = f*16 + (lane&15)
    #pragma unroll
    for (int r = 0; r < 4; ++r) {
        float s1 = D[0][r]*a1v[0] + D[1][r]*a1v[1] + D[2][r]*a1v[2] + D[3][r]*a1v[3];
        float s2 = D[0][r]*a2v[0] + D[1][r]*a2v[1] + D[2][r]*a2v[2] + D[3][r]*a2v[3];
        #pragma unroll
        for (int d = 1; d < 16; d <<= 1) {  // reduce over the 16 cols
            s1 += __shfl_xor(s1, d, 64);
            s2 += __shfl_xor(s2, d, 64);
        }
        if (col == 0) {
            int i = i0 + w * 16 + quad * 4 + r;
            g1L[i] = __builtin_amdgcn_exp2f(s1 * L2E);
            g2L[i] = __builtin_amdgcn_exp2f(s1 * (0.01f * L2E));
            E1L[i] = __builtin_amdgcn_exp2f(s2 * L2E);
            E2L[i] = __builtin_amdgcn_exp2f(s2 * (0.01f * L2E));
        }
        #pragma unroll
        for (int f = 0; f < 4; ++f)
            tb[f * 16 + col][w * 16 + quad * 4 + r] = f2bf_rne(D[f][r]);
    }
    __syncthreads();

    // emit whB: 512 chunks of 16 B (2 jg groups x 4 b x 64 lanes)
    for (int idx = tid; idx < 512; idx += 256) {
        int lane_o = idx & 63;
        int bq     = (idx >> 6) & 3;
        int jg_l   = idx >> 8;                       // 0..1
        int col_o  = lane_o & 15, quad_o = lane_o >> 4;
        u32x4 v = *(const u32x4*)&tb[bq * 16 + col_o][jg_l * 32 + quad_o * 8];
        size_t off = (((size_t)((i0 >> 5) + jg_l) * 4 + bq) * 64 + lane_o) * 8;
        *(u32x4*)&whB[off] = v;
    }
}

// ---------------------------------------------------------------------------
// k2: fused attention partials: 128 rows x one 1024-j chunk per block,
// 8 row-group waves share each staged tile. p = max(g1*E1_j, g2*E2_j) —
// no transcendentals in the hot loop. Apart stored bf16 (rsumP f32: exact
// denominator via the 5th ones-MFMA over the same bf16 p).
// Grid: (64 row-tiles, 8 j-chunks) x 512 thr. 2 blocks/CU (16 waves).
// ---------------------------------------------------------------------------
__global__ __launch_bounds__(512, 4) void k2_attn(
    const unsigned short* __restrict__ whB,
    const float* __restrict__ g1L,
    const float* __restrict__ g2L,
    const float* __restrict__ E1L,
    const float* __restrict__ E2L,
    unsigned short* __restrict__ Apart,
    float* __restrict__ rsumP)
{
    __shared__ __align__(16) unsigned short BtF[16384];  // 8 jg x 2048, 32 KB
    __shared__ __align__(16) float E1s[256];
    __shared__ __align__(16) float E2s[256];
    const int tid  = threadIdx.x;
    const int lane = tid & 63;
    const int w    = tid >> 6;       // row-group 0..7
    const int col  = lane & 15;
    const int quad = lane >> 4;
    const int i0   = blockIdx.x * 128;
    const int jb   = blockIdx.y * 1024;

    const float g1 = g1L[i0 + w * 16 + col];  // A-fragment row m = lane&15
    const float g2 = g2L[i0 + w * 16 + col];

    f32x4 D0 = (f32x4){0.f,0.f,0.f,0.f}, D1 = D0, D2 = D0, D3 = D0, Ds = D0;
    s16x8 ones;
    #pragma unroll
    for (int jj = 0; jj < 8; ++jj) ones[jj] = (short)0x3f80;  // bf16(1.0)

    for (int s = 0; s < 4; ++s) {            // 4 stages x 256 j
        __syncthreads();
        if (tid < 64)
            *(f32x4*)&E1s[tid * 4] = *(const f32x4*)&E1L[jb + (s << 8) + tid * 4];
        else if (tid < 128) {
            int t = tid - 64;
            *(f32x4*)&E2s[t * 4] = *(const f32x4*)&E2L[jb + (s << 8) + t * 4];
        }
        {   // contiguous 32 KB fragment-major copy: whB chunk -> BtF
            const unsigned short* src = whB + ((size_t)(jb >> 5) + s * 8) * 2048;
            #pragma unroll
            for (int it = 0; it < 4; ++it) {
                int idx = (tid + it * 512) * 8;      // u32x4 units * 8 ushorts
                *(u32x4*)&BtF[idx] = *(const u32x4*)&src[idx];
            }
        }
        __syncthreads();
        #pragma unroll
        for (int j0 = 0; j0 < 256; j0 += 32) {
            const int jq = j0 + quad * 8;
            f32x4 ea1 = *(const f32x4*)&E1s[jq];
            f32x4 eb1 = *(const f32x4*)&E1s[jq + 4];
            f32x4 ea2 = *(const f32x4*)&E2s[jq];
            f32x4 eb2 = *(const f32x4*)&E2s[jq + 4];
            unsigned int pb[8];
            #pragma unroll
            for (int e = 0; e < 4; ++e) {
                pb[e]     = __float_as_uint(fmaxf(g1 * ea1[e], g2 * ea2[e]));
                pb[4 + e] = __float_as_uint(fmaxf(g1 * eb1[e], g2 * eb2[e]));
            }
            union { u32x4 u4; s16x8 s8; } Au;    // pack truncated bf16 pairs
            Au.u4[0] = __builtin_amdgcn_perm(pb[1], pb[0], 0x07060302u);
            Au.u4[1] = __builtin_amdgcn_perm(pb[3], pb[2], 0x07060302u);
            Au.u4[2] = __builtin_amdgcn_perm(pb[5], pb[4], 0x07060302u);
            Au.u4[3] = __builtin_amdgcn_perm(pb[7], pb[6], 0x07060302u);
            const unsigned short* bf = &BtF[(size_t)(j0 >> 5) * 2048 + lane * 8];
            s16x8 B0 = *(const s16x8*)(bf);
            s16x8 B1 = *(const s16x8*)(bf + 512);
            s16x8 B2 = *(const s16x8*)(bf + 1024);
            s16x8 B3 = *(const s16x8*)(bf + 1536);
            D0 = __builtin_amdgcn_mfma_f32_16x16x32_bf16(Au.s8, B0, D0, 0, 0, 0);
            D1 = __builtin_amdgcn_mfma_f32_16x16x32_bf16(Au.s8, B1, D1, 0, 0, 0);
            D2 = __builtin_amdgcn_mfma_f32_16x16x32_bf16(Au.s8, B2, D2, 0, 0, 0);
            D3 = __builtin_amdgcn_mfma_f32_16x16x32_bf16(Au.s8, B3, D3, 0, 0, 0);
            Ds = __builtin_amdgcn_mfma_f32_16x16x32_bf16(Au.s8, ones, Ds, 0, 0, 0);
        }
    }

    unsigned short* Ap = Apart + (size_t)blockIdx.y * 524288;
    #pragma unroll
    for (int r = 0; r < 4; ++r) {   // D layout: row = quad*4+r, col n = 16*b + col
        int i = i0 + w * 16 + quad * 4 + r;
        Ap[(size_t)i * 64 +      col] = f2bf_rne(D0[r]);
        Ap[(size_t)i * 64 + 16 + col] = f2bf_rne(D1[r]);
        Ap[(size_t)i * 64 + 32 + col] = f2bf_rne(D2[r]);
        Ap[(size_t)i * 64 + 48 + col] = f2bf_rne(D3[r]);
        if (col == 0) rsumP[blockIdx.y * 8192 + i] = Ds[r];
    }
}

// ---------------------------------------------------------------------------
// k3: out(f32) = elu( sum_s bf2f(Apart[s]) / sum_s rsumP[s] ), x4 per thread.
// Kernel boundary = the cross-block fence (round-9 lesson). Grid: 512 x 256.
// ---------------------------------------------------------------------------
__global__ __launch_bounds__(256) void k3_combine(
    const unsigned short* __restrict__ Apart,
    const float* __restrict__ rsumP,
    float* __restrict__ out)
{
    int gid = blockIdx.x * 256 + threadIdx.x;  // 0 .. 131071
    int i  = gid >> 4;
    int c4 = (gid & 15) << 2;
    f32x4 num = (f32x4){0.f, 0.f, 0.f, 0.f};
    float den = 0.f;
    #pragma unroll
    for (int s = 0; s < 8; ++s) {
        s16x4 pv = *(const s16x4*)&Apart[(size_t)s * 524288 + (size_t)i * 64 + c4];
        #pragma unroll
        for (int e = 0; e < 4; ++e) num[e] += bf2f((unsigned short)pv[e]);
        den += rsumP[s * 8192 + i];
    }
    float rden = 1.f / den;
    f32x4 o;
    #pragma unroll
    for (int e = 0; e < 4; ++e) {
        float v = num[e] * rden;
        o[e] = v > 0.f ? v : (__builtin_amdgcn_exp2f(v * L2E) - 1.f);
    }
    *(f32x4*)&out[(size_t)i * 64 + c4] = o;
}

// ---------------------------------------------------------------------------
extern "C" void kernel_launch(void* const* d_in, const int* in_sizes, int n_in,
                              void* d_out, int out_size, void* d_ws, size_t ws_size,
                              hipStream_t stream) {
    const float* h = (const float*)d_in[0];  // 8192x128 f32
    const float* W = (const float*)d_in[1];  // 128x64 f32
    const float* a = (const float*)d_in[2];  // 128x1 f32
    float* out = (float*)d_out;              // 8192x64 f32

    char* ws = (char*)d_ws;
    unsigned short* whB   = (unsigned short*)ws;      // 1 MB fragment-major Wh^T
    float* g1L            = (float*)(ws + 1048576);   // 32 KB e^{f1}
    float* g2L            = (float*)(ws + 1081344);   // 32 KB e^{.01 f1}
    float* E1L            = (float*)(ws + 1114112);   // 32 KB e^{f2}
    float* E2L            = (float*)(ws + 1146880);   // 32 KB e^{.01 f2}
    unsigned short* Apart = (unsigned short*)(ws + 1179648);  // 8 x 8192x64 bf16 = 8 MB
    float* rsumP          = (float*)(ws + 9568256);   // 8 x 8192 f32 = 256 KB
    // total ws ~9.9 MB (ws_size ~256 MB per fill counters)

    k1_wh<<<128, 256, 0, stream>>>(h, W, a, whB, g1L, g2L, E1L, E2L);
    k2_attn<<<dim3(64, 8), 512, 0, stream>>>(whB, g1L, g2L, E1L, E2L, Apart, rsumP);
    k3_combine<<<512, 256, 0, stream>>>(Apart, rsumP, out);
}